// Round 5
// baseline (1252.937 us; speedup 1.0000x reference)
//
#include <hip/hip_runtime.h>
#include <hip/hip_bf16.h>
#include <cstdint>

#define NN   100000
#define TT   4
#define EE   250000
#define LL   2
#define NCH  49            // ceil(NN/2048)
#define EPN  (EE + NN)     // 350000
#define N64  ((size_t)NN * 64)

typedef unsigned short ushort_t;
typedef __attribute__((ext_vector_type(8))) short bf16x8;
typedef __attribute__((ext_vector_type(16))) float floatx16;
typedef __attribute__((ext_vector_type(4))) float floatx4;   // NT-load-compatible

static __device__ __forceinline__ float gelu_exact(float v) {
    return 0.5f * v * (1.0f + erff(v * 0.7071067811865476f));
}
static __device__ __forceinline__ float wave_sum64(float v) {
    #pragma unroll
    for (int m = 32; m; m >>= 1) v += __shfl_xor(v, m, 64);
    return v;
}
// fp32 -> bf16 round-to-nearest-even (finite inputs only)
static __device__ __forceinline__ ushort_t f2bf(float f) {
    unsigned u = __float_as_uint(f);
    u += 0x7FFFu + ((u >> 16) & 1u);
    return (ushort_t)(u >> 16);
}
static __device__ __forceinline__ float bf2f(ushort_t h) {
    return __uint_as_float((unsigned)h << 16);
}
// async global->LDS 16B (per-lane global addr; LDS dest = wave base + lane*16)
// AUX = cache-policy bits (2 = NT hint; policy-only, no semantic effect)
template <int AUX>
static __device__ __forceinline__ void gl_lds16(const ushort_t* g, ushort_t* l) {
    __builtin_amdgcn_global_load_lds(
        (const __attribute__((address_space(1))) void*)g,
        (__attribute__((address_space(3))) void*)l, 16, 0, AUX);
}

// ---------------------------------------------------------------------------
// Prep: all GEMM B-operands as TRANSPOSED split-bf16 planes [n][k]:
//  wcollT[l][col][d]  (K=64)   col = t*8+side*4+h, from W·a dot products
//  linwT[c][k]        (K=256)  from lin_w[k][c]
//  bprojT[l][c][kidx] (K=1024) kidx = t*256+h*64+d, val 0.25*W_src[l,t,d,h*64+c]
//  bsum[l][c] = sum_t conv_bias
// ---------------------------------------------------------------------------
__global__ __launch_bounds__(256) void k_prep(
    const float* __restrict__ Wsrc, const float* __restrict__ Wdst,
    const float* __restrict__ asrc, const float* __restrict__ adst,
    const float* __restrict__ cb, const float* __restrict__ lin_w,
    ushort_t* __restrict__ wcTh, ushort_t* __restrict__ wcTl,
    ushort_t* __restrict__ lwTh, ushort_t* __restrict__ lwTl,
    ushort_t* __restrict__ bpTh, ushort_t* __restrict__ bpTl,
    float* __restrict__ bsum)
{
    int id = blockIdx.x * 256 + threadIdx.x;   // grid = 131072 exactly
    {   // bprojT: id = ((((l*4+t)*4+h)*64 + c)*64 + d)
        int d = id & 63;
        int c = (id >> 6) & 63;
        int h = (id >> 12) & 3;
        int t = (id >> 14) & 3;
        int l = (id >> 16) & 1;
        float v = 0.25f * Wsrc[(((l * 4 + t) * 64 + d) * 256) + h * 64 + c];
        int dst = (l * 64 + c) * 1024 + (t * 256 + h * 64 + d);
        ushort_t hh = f2bf(v);
        bpTh[dst] = hh;
        bpTl[dst] = f2bf(v - bf2f(hh));
    }
    if (id < LL * 64 * 64) {   // wcollT
        int d   = id & 63;
        int col = (id >> 6) & 63;
        int l   = (id >> 12) & 1;
        int t = col >> 3, side = (col >> 2) & 1, h = col & 3;
        const float* W = side ? Wdst : Wsrc;
        const float* a = side ? adst : asrc;
        int wb = ((l * 4 + t) * 64 + d) * 256 + h * 64;
        int ab = ((l * 4 + t) * 4 + h) * 64;
        float s = 0.f;
        #pragma unroll 8
        for (int c2 = 0; c2 < 64; ++c2) s = fmaf(W[wb + c2], a[ab + c2], s);
        int dst = (l * 64 + col) * 64 + d;
        ushort_t hh = f2bf(s);
        wcTh[dst] = hh;
        wcTl[dst] = f2bf(s - bf2f(hh));
    }
    if (id < 64 * 256) {       // linwT: c = id>>8, k = id&255
        int k = id & 255, c = id >> 8;
        float v = lin_w[k * 64 + c];
        ushort_t hh = f2bf(v);
        lwTh[c * 256 + k] = hh;
        lwTl[c * 256 + k] = f2bf(v - bf2f(hh));
    }
    if (id < LL * 64) {        // bias_sum
        int l = id >> 6, c = id & 63;
        float s = 0.f;
        for (int t = 0; t < TT; ++t) s += cb[(l * 4 + t) * 64 + c];
        bsum[id] = s;
    }
}

// ---------------------------------------------------------------------------
// CSR build; scatter writes packed (src,dst) int2 -> one dirty line per edge
// ---------------------------------------------------------------------------
__global__ void k_hist(const int* __restrict__ ei, int* __restrict__ cursor) {
    int id = blockIdx.x * 256 + threadIdx.x;
    if (id >= TT * EE) return;
    int t = id / EE, e = id - t * EE;
    int d = ei[(t * 2 + 1) * EE + e];
    atomicAdd(&cursor[t * NN + d], 1);
}

__global__ __launch_bounds__(256) void k_scan1(const int* __restrict__ deg,
                                               int* __restrict__ csum) {
    int b = blockIdx.x, t = b / NCH, cc = b - t * NCH;
    int tid = threadIdx.x;
    int base = cc * 2048 + tid * 8;
    int s = 0;
    #pragma unroll
    for (int i = 0; i < 8; ++i) {
        int idx = base + i;
        if (idx < NN) s += deg[t * NN + idx] + 1;   // +1: self loop
    }
    #pragma unroll
    for (int m = 32; m; m >>= 1) s += __shfl_xor(s, m, 64);
    __shared__ int ws4[4];
    int lane = tid & 63, wid = tid >> 6;
    if (lane == 0) ws4[wid] = s;
    __syncthreads();
    if (tid == 0) csum[b] = ws4[0] + ws4[1] + ws4[2] + ws4[3];
}

__global__ void k_scan2(const int* __restrict__ csum, int* __restrict__ cbase,
                        int* __restrict__ row_ptr) {
    int t = threadIdx.x;
    if (t >= TT) return;
    int base = 0;
    for (int c = 0; c < NCH; ++c) {
        cbase[t * NCH + c] = base;
        base += csum[t * NCH + c];
    }
    row_ptr[t * (NN + 1) + NN] = base;   // = EE + NN
}

__global__ __launch_bounds__(256) void k_scan3(int* __restrict__ cursor,
                                               const int* __restrict__ cbase,
                                               int* __restrict__ row_ptr) {
    int b = blockIdx.x, t = b / NCH, cc = b - t * NCH;
    int tid = threadIdx.x, lane = tid & 63, wid = tid >> 6;
    int base = cc * 2048 + tid * 8;
    int vals[8], ts = 0;
    #pragma unroll
    for (int i = 0; i < 8; ++i) {
        int idx = base + i;
        int v = (idx < NN) ? cursor[t * NN + idx] + 1 : 0;
        vals[i] = v; ts += v;
    }
    int v = ts;
    #pragma unroll
    for (int off = 1; off < 64; off <<= 1) {
        int u = __shfl_up(v, off, 64);
        if (lane >= off) v += u;
    }
    __shared__ int wt[4];
    if (lane == 63) wt[wid] = v;
    __syncthreads();
    int wbase = 0;
    for (int w = 0; w < wid; ++w) wbase += wt[w];
    int run = cbase[t * NCH + cc] + wbase + (v - ts);
    #pragma unroll
    for (int i = 0; i < 8; ++i) {
        int idx = base + i;
        if (idx < NN) {
            row_ptr[t * (NN + 1) + idx] = run;
            cursor[t * NN + idx] = run;     // becomes scatter write-head
        }
        run += vals[i];
    }
}

__global__ void k_scatter(const int* __restrict__ ei, int* __restrict__ cursor,
                          int2* __restrict__ sd) {
    int id = blockIdx.x * 256 + threadIdx.x;
    if (id >= TT * EPN) return;
    int t = id / EPN, r = id - t * EPN;
    int s, d;
    if (r < EE) { s = ei[t * 2 * EE + r]; d = ei[(t * 2 + 1) * EE + r]; }
    else        { s = d = r - EE; }
    int pos = atomicAdd(&cursor[t * NN + d], 1);
    sd[(size_t)t * EPN + pos] = make_int2(s, d);
}

// ---------------------------------------------------------------------------
// Split-bf16 MFMA GEMM: C[N,64] = A[N,K] @ B[K,64] via 3 products
// (ah·bh + al·bh + ah·bl), mfma_f32_32x32x16_bf16.
// LDS layout: linear 64B rows (LK=32 shorts), XOR chunk-swizzle on the
// GLOBAL source side:  LDS[r][c] = A[r][c ^ sg(r)],  sg(r)=(r^(r>>2))&3.
// bf16 path stages via global_load_lds width-16 (direct-to-LDS, linear dest);
// fp32 path (FLAGS&8) splits during staging via register writes.
// Fragment layouts (verified m74/m101/m120-lineage):
//   A[m][k]: m=lane&31, k=(lane>>5)*8+j    B[k][n]: n=lane&31, same k
//   C/D: col=lane&31 (+32*ct), row=(reg&3)+8*(reg>>2)+4*(lane>>5)
// FLAGS bit0: +accbuf; bit1: gelu((v+bias)*0.25); bit3: A fp32; bit4: A NT
// ---------------------------------------------------------------------------
template <int FLAGS>
__global__ __launch_bounds__(256, 4) void k_gemm_mx(
    const ushort_t* __restrict__ Ahi, const ushort_t* __restrict__ Alo,
    const ushort_t* __restrict__ Bhi, const ushort_t* __restrict__ Blo,
    int K, int ldb, int nrows,
    const float* __restrict__ accbuf, const float* __restrict__ bias,
    float* __restrict__ Cout)
{
    constexpr int KC = 32;
    constexpr int AAUX = (FLAGS & 16) ? 2 : 0;   // NT cache hint for A stream
    __shared__ ushort_t sAh[128 * 32], sAl[128 * 32];
    __shared__ ushort_t sBh[64 * 32],  sBl[64 * 32];
    const int tid = threadIdx.x;
    const int w = tid >> 6, ln = tid & 63;
    const int l31 = ln & 31, hl = ln >> 5;
    const int rowbase = blockIdx.x * 128;

    floatx16 accv[2];
    #pragma unroll
    for (int ct = 0; ct < 2; ++ct)
        #pragma unroll
        for (int r = 0; r < 16; ++r) accv[ct][r] = 0.f;

    for (int kc = 0; kc < K; kc += KC) {
        __syncthreads();
        // stage A: 128 rows x 32 k (4 chunks of 8 shorts), both planes
        #pragma unroll
        for (int i = 0; i < 2; ++i) {
            int f = tid + i * 256;           // 0..511
            int r = f >> 2, cg = f & 3;
            int row = rowbase + r;
            int sg = (r ^ (r >> 2)) & 3;
            if constexpr (FLAGS & 8) {
                // load global chunk cg, store to LDS slot cg^sg
                int sw = r * 32 + ((cg ^ sg) << 3);
                if (row < nrows) {
                    const float* Af = (const float*)Ahi;
                    size_t ga = (size_t)row * K + kc + cg * 8;
                    floatx4 v0, v1;
                    if constexpr (FLAGS & 16) {
                        v0 = __builtin_nontemporal_load((const floatx4*)(Af + ga));
                        v1 = __builtin_nontemporal_load((const floatx4*)(Af + ga + 4));
                    } else {
                        v0 = *(const floatx4*)(Af + ga);
                        v1 = *(const floatx4*)(Af + ga + 4);
                    }
                    float vf[8] = {v0.x, v0.y, v0.z, v0.w, v1.x, v1.y, v1.z, v1.w};
                    unsigned hu[8], lu[8];
                    #pragma unroll
                    for (int q = 0; q < 8; ++q) {
                        ushort_t hh = f2bf(vf[q]);
                        hu[q] = hh;
                        lu[q] = f2bf(vf[q] - bf2f(hh));
                    }
                    uint4 H = make_uint4(hu[0] | (hu[1] << 16), hu[2] | (hu[3] << 16),
                                         hu[4] | (hu[5] << 16), hu[6] | (hu[7] << 16));
                    uint4 L = make_uint4(lu[0] | (lu[1] << 16), lu[2] | (lu[3] << 16),
                                         lu[4] | (lu[5] << 16), lu[6] | (lu[7] << 16));
                    *(uint4*)&sAh[sw] = H;
                    *(uint4*)&sAl[sw] = L;
                } else {
                    *(uint4*)&sAh[sw] = make_uint4(0, 0, 0, 0);
                    *(uint4*)&sAl[sw] = make_uint4(0, 0, 0, 0);
                }
            } else {
                // direct-to-LDS: global chunk cg^sg -> linear LDS slot cg
                // (LDS dest bytes = wave_base + lane*16: r*64+cg*16 == ln*16 + base)
                int so = r * 32 + (cg << 3);
                size_t ga = (size_t)row * K + kc + ((cg ^ sg) << 3);
                if (row < nrows) {               // masked lanes: stale LDS, rows discarded
                    gl_lds16<AAUX>(Ahi + ga, &sAh[so]);
                    gl_lds16<AAUX>(Alo + ga, &sAl[so]);
                }
            }
        }
        // stage B: 64 n-rows x 32 k, both planes, direct-to-LDS
        {
            int r = tid >> 2, cg = tid & 3;
            int sg = (r ^ (r >> 2)) & 3;
            int so = r * 32 + (cg << 3);
            size_t gb = (size_t)r * ldb + kc + ((cg ^ sg) << 3);
            gl_lds16<0>(Bhi + gb, &sBh[so]);
            gl_lds16<0>(Blo + gb, &sBl[so]);
        }
        __syncthreads();
        const int arow = (w << 5) + l31;
        const int sga = (arow ^ (arow >> 2)) & 3;
        const int sgb = (l31 ^ (l31 >> 2)) & 3;   // same for row l31 and 32+l31
        #pragma unroll
        for (int s = 0; s < 2; ++s) {
            const int c0 = (s << 1) | hl;          // k-chunk index 0..3
            const int ka = (c0 ^ sga) << 3;
            const int kb = (c0 ^ sgb) << 3;
            bf16x8 ah  = *(const bf16x8*)&sAh[arow * 32 + ka];
            bf16x8 al  = *(const bf16x8*)&sAl[arow * 32 + ka];
            bf16x8 bh0 = *(const bf16x8*)&sBh[l31 * 32 + kb];
            bf16x8 bl0 = *(const bf16x8*)&sBl[l31 * 32 + kb];
            bf16x8 bh1 = *(const bf16x8*)&sBh[(32 + l31) * 32 + kb];
            bf16x8 bl1 = *(const bf16x8*)&sBl[(32 + l31) * 32 + kb];
            accv[0] = __builtin_amdgcn_mfma_f32_32x32x16_bf16(ah, bh0, accv[0], 0, 0, 0);
            accv[1] = __builtin_amdgcn_mfma_f32_32x32x16_bf16(ah, bh1, accv[1], 0, 0, 0);
            accv[0] = __builtin_amdgcn_mfma_f32_32x32x16_bf16(al, bh0, accv[0], 0, 0, 0);
            accv[1] = __builtin_amdgcn_mfma_f32_32x32x16_bf16(al, bh1, accv[1], 0, 0, 0);
            accv[0] = __builtin_amdgcn_mfma_f32_32x32x16_bf16(ah, bl0, accv[0], 0, 0, 0);
            accv[1] = __builtin_amdgcn_mfma_f32_32x32x16_bf16(ah, bl1, accv[1], 0, 0, 0);
        }
    }
    // epilogue
    #pragma unroll
    for (int ct = 0; ct < 2; ++ct) {
        int col = (ct << 5) + l31;
        float bv = (FLAGS & 2) ? bias[col] : 0.f;
        #pragma unroll
        for (int r = 0; r < 16; ++r) {
            int row = rowbase + (w << 5) + (r & 3) + ((r >> 2) << 3) + (hl << 2);
            if (row < nrows) {
                size_t idx = (size_t)row * 64 + col;
                float v = accv[ct][r];
                if (FLAGS & 1) v += accbuf[idx];
                if (FLAGS & 2) v = gelu_exact((v + bv) * 0.25f);
                Cout[idx] = v;
            }
        }
    }
}

// ---------------------------------------------------------------------------
// Feature epilogue: x = gelu(LN(y + lin_b)) + l2norm(emb)  (fp32 only)
// ---------------------------------------------------------------------------
__global__ __launch_bounds__(256) void k_feat_post(
    const float* __restrict__ y, const float* __restrict__ lin_b,
    const float* __restrict__ ln_g, const float* __restrict__ ln_b,
    const float* __restrict__ emb, float* __restrict__ xout)
{
    int n = (blockIdx.x << 2) + (threadIdx.x >> 6);
    int c = threadIdx.x & 63;
    size_t base = (size_t)n * 64 + c;
    float v = y[base] + lin_b[c];
    float mean = wave_sum64(v) * 0.015625f;
    float t = v - mean;
    float var = wave_sum64(t * t) * 0.015625f;
    float vn = t * (1.0f / sqrtf(var + 1e-5f)) * ln_g[c] + ln_b[c];
    float g = gelu_exact(vn);
    float e = emb[base];
    float nrm = sqrtf(wave_sum64(e * e));
    float xv = g + e / fmaxf(nrm, 1e-12f);
    xout[base] = xv;
}

// ---------------------------------------------------------------------------
// Edge-parallel softmax numerator: one lane = one CSR slot.
// p[t][e][h] = exp(leakyrelu(s_all[src][t*8+h] + s_all[dst][t*8+4+h]))
// ---------------------------------------------------------------------------
__global__ __launch_bounds__(256) void k_edgep(
    const float* __restrict__ s_all, const int2* __restrict__ sd,
    float* __restrict__ parr)
{
    int i = blockIdx.x * 256 + threadIdx.x;
    int t = blockIdx.y;
    if (i >= EPN) return;
    size_t base = (size_t)t * EPN + i;
    int2 e = sd[base];
    const float4 a = *(const float4*)&s_all[(size_t)e.x * 64 + t * 8];
    const float4 b = *(const float4*)&s_all[(size_t)e.y * 64 + t * 8 + 4];
    float l0 = a.x + b.x, l1 = a.y + b.y;
    float l2 = a.z + b.z, l3 = a.w + b.w;
    l0 = l0 > 0.f ? l0 : 0.2f * l0;
    l1 = l1 > 0.f ? l1 : 0.2f * l1;
    l2 = l2 > 0.f ? l2 : 0.2f * l2;
    l3 = l3 > 0.f ? l3 : 0.2f * l3;
    float4 p = make_float4(__expf(l0), __expf(l1), __expf(l2), __expf(l3));
    *(float4*)&parr[base * 4] = p;
}

// ---------------------------------------------------------------------------
// Edge aggregation for a TYPE PAIR (t0, t0+1) -> split-bf16 z planes [N][512].
// ONE WAVE PER (node, type): grid = NN/2 blocks; id = blk*4+wave;
// n = id>>1, t = t0 + (id&1).  Short (~3.5-iter) independent gather loops;
// NT loads for single-use sd/p, NT stores for the single-use z stream so the
// hot x working set stays cache-resident.
// z[n][(t-t0)*256+h*64+d] = (sum_e p_e,h * x[src_e,d]) / S[n,h]
// ---------------------------------------------------------------------------
__global__ __launch_bounds__(256) void k_edge2(
    const float* __restrict__ x, const float* __restrict__ parr,
    const int* __restrict__ row_ptr, const int2* __restrict__ sd,
    ushort_t* __restrict__ zh, ushort_t* __restrict__ zl, int t0)
{
    int id = (blockIdx.x << 2) + (threadIdx.x >> 6);   // grid = NN/2 exactly
    int lane = threadIdx.x & 63;
    int n = id >> 1;
    int tt = id & 1;
    int t = t0 + tt;
    int e0 = row_ptr[t * (NN + 1) + n];
    int e1 = row_ptr[t * (NN + 1) + n + 1];
    const int*     srcs = (const int*)(sd + (size_t)t * EPN);   // .x at stride 2
    const floatx4* pt   = (const floatx4*)parr + (size_t)t * EPN;
    float z0 = 0.f, z1 = 0.f, z2 = 0.f, z3 = 0.f;
    float S0 = 0.f, S1 = 0.f, S2 = 0.f, S3 = 0.f;
    #pragma unroll 4
    for (int e = e0; e < e1; ++e) {
        int s = __builtin_nontemporal_load(srcs + 2 * e);     // wave-uniform
        floatx4 p = __builtin_nontemporal_load(pt + e);       // wave-uniform 16B
        float xv = x[(size_t)s * 64 + lane];                  // coalesced 256B
        S0 += p.x; S1 += p.y; S2 += p.z; S3 += p.w;
        z0 = fmaf(p.x, xv, z0);
        z1 = fmaf(p.y, xv, z1);
        z2 = fmaf(p.z, xv, z2);
        z3 = fmaf(p.w, xv, z3);
    }
    size_t zb = (size_t)n * 512 + tt * 256 + lane;
    float v0 = z0 / S0, v1 = z1 / S1, v2 = z2 / S2, v3 = z3 / S3;
    ushort_t h0 = f2bf(v0), h1 = f2bf(v1), h2 = f2bf(v2), h3 = f2bf(v3);
    __builtin_nontemporal_store(h0, &zh[zb]);
    __builtin_nontemporal_store(h1, &zh[zb + 64]);
    __builtin_nontemporal_store(h2, &zh[zb + 128]);
    __builtin_nontemporal_store(h3, &zh[zb + 192]);
    __builtin_nontemporal_store(f2bf(v0 - bf2f(h0)), &zl[zb]);
    __builtin_nontemporal_store(f2bf(v1 - bf2f(h1)), &zl[zb + 64]);
    __builtin_nontemporal_store(f2bf(v2 - bf2f(h2)), &zl[zb + 128]);
    __builtin_nontemporal_store(f2bf(v3 - bf2f(h3)), &zl[zb + 192]);
}

// ---------------------------------------------------------------------------
extern "C" void kernel_launch(void* const* d_in, const int* in_sizes, int n_in,
                              void* d_out, int out_size, void* d_ws, size_t ws_size,
                              hipStream_t stream) {
    const float* fm    = (const float*)d_in[0];
    const float* emb   = (const float*)d_in[1];
    const float* lin_w = (const float*)d_in[2];
    const float* lin_b = (const float*)d_in[3];
    const float* ln_g  = (const float*)d_in[4];
    const float* ln_b  = (const float*)d_in[5];
    const float* Wsrc  = (const float*)d_in[6];
    const float* Wdst  = (const float*)d_in[7];
    const float* asrc  = (const float*)d_in[8];
    const float* adst  = (const float*)d_in[9];
    const float* cbias = (const float*)d_in[10];
    const int*   ei    = (const int*)d_in[11];
    float* out = (float*)d_out;
    (void)in_sizes; (void)n_in; (void)out_size; (void)ws_size;

    char* w = (char*)d_ws;
    size_t off = 0;
    auto alloc = [&](size_t bytes) -> void* {
        void* p = w + off;
        off += (bytes + 255) & ~(size_t)255;
        return p;
    };
    ushort_t* wcTh = (ushort_t*)alloc((size_t)LL * 64 * 64 * 2);
    ushort_t* wcTl = (ushort_t*)alloc((size_t)LL * 64 * 64 * 2);
    ushort_t* lwTh = (ushort_t*)alloc((size_t)64 * 256 * 2);
    ushort_t* lwTl = (ushort_t*)alloc((size_t)64 * 256 * 2);
    ushort_t* bpTh = (ushort_t*)alloc((size_t)LL * 64 * 1024 * 2);
    ushort_t* bpTl = (ushort_t*)alloc((size_t)LL * 64 * 1024 * 2);
    float* bsum    = (float*)alloc((size_t)LL * 64 * 4);
    int*   row_ptr = (int*)  alloc((size_t)TT * (NN + 1) * 4);
    int*   cursor  = (int*)  alloc((size_t)TT * NN * 4);
    int2*  sdarr   = (int2*) alloc((size_t)TT * EPN * 8);
    float* parr    = (float*)alloc((size_t)TT * EPN * 4 * 4);
    int*   csum    = (int*)  alloc((size_t)TT * NCH * 4);
    int*   cbase   = (int*)  alloc((size_t)TT * NCH * 4);
    float* x       = (float*)alloc(N64 * 4);
    float* s_all   = (float*)alloc(N64 * 4);
    float* accB    = (float*)alloc(N64 * 4);
    // z split planes for one type pair: [N][512] hi + lo  (204.8 MB)
    size_t planeE = (size_t)NN * 512;
    ushort_t* zh = (ushort_t*)alloc(2 * planeE * 2);
    ushort_t* zl = zh + planeE;

    hipMemsetAsync(cursor, 0, (size_t)TT * NN * 4, stream);
    k_prep<<<512, 256, 0, stream>>>(Wsrc, Wdst, asrc, adst, cbias, lin_w,
                                    wcTh, wcTl, lwTh, lwTl, bpTh, bpTl, bsum);
    k_hist<<<(TT * EE + 255) / 256, 256, 0, stream>>>(ei, cursor);
    k_scan1<<<TT * NCH, 256, 0, stream>>>(cursor, csum);
    k_scan2<<<1, 64, 0, stream>>>(csum, cbase, row_ptr);
    k_scan3<<<TT * NCH, 256, 0, stream>>>(cursor, cbase, row_ptr);
    k_scatter<<<(TT * EPN + 255) / 256, 256, 0, stream>>>(ei, cursor, sdarr);

    const int GB = (NN + 127) / 128;   // 782 blocks (128 rows each)
    // feature transform: GEMM K=256, fp32 A (split in staging) + NT A stream
    k_gemm_mx<24><<<GB, 256, 0, stream>>>((const ushort_t*)fm, nullptr,
                                          lwTh, lwTl, 256, 256, NN,
                                          nullptr, nullptr, accB);
    k_feat_post<<<NN / 4, 256, 0, stream>>>(accB, lin_b, ln_g, ln_b, emb, x);

    const dim3 gp((EPN + 255) / 256, TT);
    for (int l = 0; l < LL; ++l) {
        float* dest = (l == 0) ? x : out;
        // collapsed attention-logit projection: s_all = x @ wcoll_l  [N,64]
        // (x is hot/reused by edge2 — no NT here)
        k_gemm_mx<8><<<GB, 256, 0, stream>>>((const ushort_t*)x, nullptr,
                                             wcTh + l * 4096, wcTl + l * 4096,
                                             64, 64, NN, nullptr, nullptr, s_all);
        // edge-parallel p = exp(leaky(logit)) for all 4 types of this layer
        k_edgep<<<gp, 256, 0, stream>>>(s_all, sdarr, parr);
        const ushort_t* Bh = bpTh + (size_t)l * 65536;
        const ushort_t* Bl = bpTl + (size_t)l * 65536;
        // pair 0 (types 0,1): aggregate + GEMM K=512 (NT A) -> accB
        k_edge2<<<NN / 2, 256, 0, stream>>>(x, parr, row_ptr, sdarr, zh, zl, 0);
        k_gemm_mx<16><<<GB, 256, 0, stream>>>(zh, zl, Bh, Bl, 512, 1024, NN,
                                              nullptr, nullptr, accB);
        // pair 1 (types 2,3): aggregate + GEMM K=512 (NT A) + acc + gelu -> dest
        k_edge2<<<NN / 2, 256, 0, stream>>>(x, parr, row_ptr, sdarr, zh, zl, 2);
        k_gemm_mx<19><<<GB, 256, 0, stream>>>(zh, zl, Bh + 512, Bl + 512, 512, 1024,
                                              NN, accB, bsum + l * 64, dest);
    }
}

// Round 6
// 1224.846 us; speedup vs baseline: 1.0229x; 1.0229x over previous
//
#include <hip/hip_runtime.h>
#include <hip/hip_bf16.h>
#include <cstdint>

#define NN   100000
#define TT   4
#define EE   250000
#define LL   2
#define NCH  49            // ceil(NN/2048)
#define EPN  (EE + NN)     // 350000
#define N64  ((size_t)NN * 64)

typedef unsigned short ushort_t;
typedef __attribute__((ext_vector_type(8))) short bf16x8;
typedef __attribute__((ext_vector_type(16))) float floatx16;
typedef __attribute__((ext_vector_type(4))) float floatx4;

static __device__ __forceinline__ float gelu_exact(float v) {
    return 0.5f * v * (1.0f + erff(v * 0.7071067811865476f));
}
static __device__ __forceinline__ float wave_sum64(float v) {
    #pragma unroll
    for (int m = 32; m; m >>= 1) v += __shfl_xor(v, m, 64);
    return v;
}
// fp32 -> bf16 round-to-nearest-even (finite inputs only)
static __device__ __forceinline__ ushort_t f2bf(float f) {
    unsigned u = __float_as_uint(f);
    u += 0x7FFFu + ((u >> 16) & 1u);
    return (ushort_t)(u >> 16);
}
static __device__ __forceinline__ float bf2f(ushort_t h) {
    return __uint_as_float((unsigned)h << 16);
}
// async global->LDS 16B (per-lane global addr; LDS dest = wave base + lane*16)
static __device__ __forceinline__ void gl_lds16(const ushort_t* g, ushort_t* l) {
    __builtin_amdgcn_global_load_lds(
        (const __attribute__((address_space(1))) void*)g,
        (__attribute__((address_space(3))) void*)l, 16, 0, 0);
}

// ---------------------------------------------------------------------------
// Prep: GEMM B-operands as TRANSPOSED split-bf16 planes [n][k]:
//  wcollT[l][col][d]  (K=64)   col = t*8+side*4+h, from W·a dot products
//  linwT[c][k]        (K=256)  from lin_w[k][c]
//  bprojT[l][c][kidx] (K=1024) kidx = t*256 + d*4 + h  (d-major, h-minor so a
//                     lane's 4 head values are k-contiguous in the z layout)
//  bsum[l][c] = sum_t conv_bias
// ---------------------------------------------------------------------------
__global__ __launch_bounds__(256) void k_prep(
    const float* __restrict__ Wsrc, const float* __restrict__ Wdst,
    const float* __restrict__ asrc, const float* __restrict__ adst,
    const float* __restrict__ cb, const float* __restrict__ lin_w,
    ushort_t* __restrict__ wcTh, ushort_t* __restrict__ wcTl,
    ushort_t* __restrict__ lwTh, ushort_t* __restrict__ lwTl,
    ushort_t* __restrict__ bpTh, ushort_t* __restrict__ bpTl,
    float* __restrict__ bsum)
{
    int id = blockIdx.x * 256 + threadIdx.x;   // grid = 131072 exactly
    {   // bprojT: id = ((((l*4+t)*4+h)*64 + c)*64 + d)
        int d = id & 63;
        int c = (id >> 6) & 63;
        int h = (id >> 12) & 3;
        int t = (id >> 14) & 3;
        int l = (id >> 16) & 1;
        float v = 0.25f * Wsrc[(((l * 4 + t) * 64 + d) * 256) + h * 64 + c];
        int dst = (l * 64 + c) * 1024 + (t * 256 + d * 4 + h);
        ushort_t hh = f2bf(v);
        bpTh[dst] = hh;
        bpTl[dst] = f2bf(v - bf2f(hh));
    }
    if (id < LL * 64 * 64) {   // wcollT
        int d   = id & 63;
        int col = (id >> 6) & 63;
        int l   = (id >> 12) & 1;
        int t = col >> 3, side = (col >> 2) & 1, h = col & 3;
        const float* W = side ? Wdst : Wsrc;
        const float* a = side ? adst : asrc;
        int wb = ((l * 4 + t) * 64 + d) * 256 + h * 64;
        int ab = ((l * 4 + t) * 4 + h) * 64;
        float s = 0.f;
        #pragma unroll 8
        for (int c2 = 0; c2 < 64; ++c2) s = fmaf(W[wb + c2], a[ab + c2], s);
        int dst = (l * 64 + col) * 64 + d;
        ushort_t hh = f2bf(s);
        wcTh[dst] = hh;
        wcTl[dst] = f2bf(s - bf2f(hh));
    }
    if (id < 64 * 256) {       // linwT: c = id>>8, k = id&255
        int k = id & 255, c = id >> 8;
        float v = lin_w[k * 64 + c];
        ushort_t hh = f2bf(v);
        lwTh[c * 256 + k] = hh;
        lwTl[c * 256 + k] = f2bf(v - bf2f(hh));
    }
    if (id < LL * 64) {        // bias_sum
        int l = id >> 6, c = id & 63;
        float s = 0.f;
        for (int t = 0; t < TT; ++t) s += cb[(l * 4 + t) * 64 + c];
        bsum[id] = s;
    }
}

// ---------------------------------------------------------------------------
// CSR build; scatter writes packed (src,dst) int2 -> one dirty line per edge
// ---------------------------------------------------------------------------
__global__ void k_hist(const int* __restrict__ ei, int* __restrict__ cursor) {
    int id = blockIdx.x * 256 + threadIdx.x;
    if (id >= TT * EE) return;
    int t = id / EE, e = id - t * EE;
    int d = ei[(t * 2 + 1) * EE + e];
    atomicAdd(&cursor[t * NN + d], 1);
}

__global__ __launch_bounds__(256) void k_scan1(const int* __restrict__ deg,
                                               int* __restrict__ csum) {
    int b = blockIdx.x, t = b / NCH, cc = b - t * NCH;
    int tid = threadIdx.x;
    int base = cc * 2048 + tid * 8;
    int s = 0;
    #pragma unroll
    for (int i = 0; i < 8; ++i) {
        int idx = base + i;
        if (idx < NN) s += deg[t * NN + idx] + 1;   // +1: self loop
    }
    #pragma unroll
    for (int m = 32; m; m >>= 1) s += __shfl_xor(s, m, 64);
    __shared__ int ws4[4];
    int lane = tid & 63, wid = tid >> 6;
    if (lane == 0) ws4[wid] = s;
    __syncthreads();
    if (tid == 0) csum[b] = ws4[0] + ws4[1] + ws4[2] + ws4[3];
}

__global__ void k_scan2(const int* __restrict__ csum, int* __restrict__ cbase,
                        int* __restrict__ row_ptr) {
    int t = threadIdx.x;
    if (t >= TT) return;
    int base = 0;
    for (int c = 0; c < NCH; ++c) {
        cbase[t * NCH + c] = base;
        base += csum[t * NCH + c];
    }
    row_ptr[t * (NN + 1) + NN] = base;   // = EE + NN
}

__global__ __launch_bounds__(256) void k_scan3(int* __restrict__ cursor,
                                               const int* __restrict__ cbase,
                                               int* __restrict__ row_ptr) {
    int b = blockIdx.x, t = b / NCH, cc = b - t * NCH;
    int tid = threadIdx.x, lane = tid & 63, wid = tid >> 6;
    int base = cc * 2048 + tid * 8;
    int vals[8], ts = 0;
    #pragma unroll
    for (int i = 0; i < 8; ++i) {
        int idx = base + i;
        int v = (idx < NN) ? cursor[t * NN + idx] + 1 : 0;
        vals[i] = v; ts += v;
    }
    int v = ts;
    #pragma unroll
    for (int off = 1; off < 64; off <<= 1) {
        int u = __shfl_up(v, off, 64);
        if (lane >= off) v += u;
    }
    __shared__ int wt[4];
    if (lane == 63) wt[wid] = v;
    __syncthreads();
    int wbase = 0;
    for (int w = 0; w < wid; ++w) wbase += wt[w];
    int run = cbase[t * NCH + cc] + wbase + (v - ts);
    #pragma unroll
    for (int i = 0; i < 8; ++i) {
        int idx = base + i;
        if (idx < NN) {
            row_ptr[t * (NN + 1) + idx] = run;
            cursor[t * NN + idx] = run;     // becomes scatter write-head
        }
        run += vals[i];
    }
}

__global__ void k_scatter(const int* __restrict__ ei, int* __restrict__ cursor,
                          int2* __restrict__ sd) {
    int id = blockIdx.x * 256 + threadIdx.x;
    if (id >= TT * EPN) return;
    int t = id / EPN, r = id - t * EPN;
    int s, d;
    if (r < EE) { s = ei[t * 2 * EE + r]; d = ei[(t * 2 + 1) * EE + r]; }
    else        { s = d = r - EE; }
    int pos = atomicAdd(&cursor[t * NN + d], 1);
    sd[(size_t)t * EPN + pos] = make_int2(s, d);
}

// ---------------------------------------------------------------------------
// Split-bf16 MFMA GEMM (feature transform + s_all projection only).
// C[N,64] = A[N,K] @ B[K,64], A fp32 split into hi/lo during LDS staging.
// LDS: linear 64B rows, XOR chunk-swizzle applied on the source side.
// Fragment layouts (verified m74/m101/m120-lineage):
//   A[m][k]: m=lane&31, k=(lane>>5)*8+j    B[k][n]: n=lane&31, same k
//   C/D: col=lane&31 (+32*ct), row=(reg&3)+8*(reg>>2)+4*(lane>>5)
// ---------------------------------------------------------------------------
__global__ __launch_bounds__(256, 4) void k_gemm_f32a(
    const float* __restrict__ Af,
    const ushort_t* __restrict__ Bhi, const ushort_t* __restrict__ Blo,
    int K, int ldb, int nrows, float* __restrict__ Cout)
{
    constexpr int KC = 32;
    __shared__ ushort_t sAh[128 * 32], sAl[128 * 32];
    __shared__ ushort_t sBh[64 * 32],  sBl[64 * 32];
    const int tid = threadIdx.x;
    const int w = tid >> 6, ln = tid & 63;
    const int l31 = ln & 31, hl = ln >> 5;
    const int rowbase = blockIdx.x * 128;

    floatx16 accv[2];
    #pragma unroll
    for (int ct = 0; ct < 2; ++ct)
        #pragma unroll
        for (int r = 0; r < 16; ++r) accv[ct][r] = 0.f;

    for (int kc = 0; kc < K; kc += KC) {
        __syncthreads();
        // stage A: 128 rows x 32 k (4 chunks of 8), fp32 -> split-bf16
        #pragma unroll
        for (int i = 0; i < 2; ++i) {
            int f = tid + i * 256;           // 0..511
            int r = f >> 2, cg = f & 3;
            int row = rowbase + r;
            int sg = (r ^ (r >> 2)) & 3;
            int sw = r * 32 + ((cg ^ sg) << 3);
            if (row < nrows) {
                size_t ga = (size_t)row * K + kc + cg * 8;
                floatx4 v0 = *(const floatx4*)(Af + ga);
                floatx4 v1 = *(const floatx4*)(Af + ga + 4);
                float vf[8] = {v0.x, v0.y, v0.z, v0.w, v1.x, v1.y, v1.z, v1.w};
                unsigned hu[8], lu[8];
                #pragma unroll
                for (int q = 0; q < 8; ++q) {
                    ushort_t hh = f2bf(vf[q]);
                    hu[q] = hh;
                    lu[q] = f2bf(vf[q] - bf2f(hh));
                }
                uint4 H = make_uint4(hu[0] | (hu[1] << 16), hu[2] | (hu[3] << 16),
                                     hu[4] | (hu[5] << 16), hu[6] | (hu[7] << 16));
                uint4 L = make_uint4(lu[0] | (lu[1] << 16), lu[2] | (lu[3] << 16),
                                     lu[4] | (lu[5] << 16), lu[6] | (lu[7] << 16));
                *(uint4*)&sAh[sw] = H;
                *(uint4*)&sAl[sw] = L;
            } else {
                *(uint4*)&sAh[sw] = make_uint4(0, 0, 0, 0);
                *(uint4*)&sAl[sw] = make_uint4(0, 0, 0, 0);
            }
        }
        // stage B: 64 n-rows x 32 k, both planes, direct-to-LDS
        {
            int r = tid >> 2, cg = tid & 3;
            int sg = (r ^ (r >> 2)) & 3;
            int so = r * 32 + (cg << 3);
            size_t gb = (size_t)r * ldb + kc + ((cg ^ sg) << 3);
            gl_lds16(Bhi + gb, &sBh[so]);
            gl_lds16(Blo + gb, &sBl[so]);
        }
        __syncthreads();
        const int arow = (w << 5) + l31;
        const int sga = (arow ^ (arow >> 2)) & 3;
        const int sgb = (l31 ^ (l31 >> 2)) & 3;
        #pragma unroll
        for (int s = 0; s < 2; ++s) {
            const int c0 = (s << 1) | hl;
            const int ka = (c0 ^ sga) << 3;
            const int kb = (c0 ^ sgb) << 3;
            bf16x8 ah  = *(const bf16x8*)&sAh[arow * 32 + ka];
            bf16x8 al  = *(const bf16x8*)&sAl[arow * 32 + ka];
            bf16x8 bh0 = *(const bf16x8*)&sBh[l31 * 32 + kb];
            bf16x8 bl0 = *(const bf16x8*)&sBl[l31 * 32 + kb];
            bf16x8 bh1 = *(const bf16x8*)&sBh[(32 + l31) * 32 + kb];
            bf16x8 bl1 = *(const bf16x8*)&sBl[(32 + l31) * 32 + kb];
            accv[0] = __builtin_amdgcn_mfma_f32_32x32x16_bf16(ah, bh0, accv[0], 0, 0, 0);
            accv[1] = __builtin_amdgcn_mfma_f32_32x32x16_bf16(ah, bh1, accv[1], 0, 0, 0);
            accv[0] = __builtin_amdgcn_mfma_f32_32x32x16_bf16(al, bh0, accv[0], 0, 0, 0);
            accv[1] = __builtin_amdgcn_mfma_f32_32x32x16_bf16(al, bh1, accv[1], 0, 0, 0);
            accv[0] = __builtin_amdgcn_mfma_f32_32x32x16_bf16(ah, bl0, accv[0], 0, 0, 0);
            accv[1] = __builtin_amdgcn_mfma_f32_32x32x16_bf16(ah, bl1, accv[1], 0, 0, 0);
        }
    }
    #pragma unroll
    for (int ct = 0; ct < 2; ++ct) {
        int col = (ct << 5) + l31;
        #pragma unroll
        for (int r = 0; r < 16; ++r) {
            int row = rowbase + (w << 5) + (r & 3) + ((r >> 2) << 3) + (hl << 2);
            if (row < nrows) Cout[(size_t)row * 64 + col] = accv[ct][r];
        }
    }
}

// ---------------------------------------------------------------------------
// Feature epilogue: x = gelu(LN(y + lin_b)) + l2norm(emb)
// ---------------------------------------------------------------------------
__global__ __launch_bounds__(256) void k_feat_post(
    const float* __restrict__ y, const float* __restrict__ lin_b,
    const float* __restrict__ ln_g, const float* __restrict__ ln_b,
    const float* __restrict__ emb, float* __restrict__ xout)
{
    int n = (blockIdx.x << 2) + (threadIdx.x >> 6);
    int c = threadIdx.x & 63;
    size_t base = (size_t)n * 64 + c;
    float v = y[base] + lin_b[c];
    float mean = wave_sum64(v) * 0.015625f;
    float t = v - mean;
    float var = wave_sum64(t * t) * 0.015625f;
    float vn = t * (1.0f / sqrtf(var + 1e-5f)) * ln_g[c] + ln_b[c];
    float g = gelu_exact(vn);
    float e = emb[base];
    float nrm = sqrtf(wave_sum64(e * e));
    float xv = g + e / fmaxf(nrm, 1e-12f);
    xout[base] = xv;
}

// ---------------------------------------------------------------------------
// Edge-parallel softmax numerator: one lane = one CSR slot.
// p[t][e][h] = exp(leakyrelu(s_all[src][t*8+h] + s_all[dst][t*8+4+h]))
// ---------------------------------------------------------------------------
__global__ __launch_bounds__(256) void k_edgep(
    const float* __restrict__ s_all, const int2* __restrict__ sd,
    float* __restrict__ parr)
{
    int i = blockIdx.x * 256 + threadIdx.x;
    int t = blockIdx.y;
    if (i >= EPN) return;
    size_t base = (size_t)t * EPN + i;
    int2 e = sd[base];
    const float4 a = *(const float4*)&s_all[(size_t)e.x * 64 + t * 8];
    const float4 b = *(const float4*)&s_all[(size_t)e.y * 64 + t * 8 + 4];
    float l0 = a.x + b.x, l1 = a.y + b.y;
    float l2 = a.z + b.z, l3 = a.w + b.w;
    l0 = l0 > 0.f ? l0 : 0.2f * l0;
    l1 = l1 > 0.f ? l1 : 0.2f * l1;
    l2 = l2 > 0.f ? l2 : 0.2f * l2;
    l3 = l3 > 0.f ? l3 : 0.2f * l3;
    float4 p = make_float4(__expf(l0), __expf(l1), __expf(l2), __expf(l3));
    *(float4*)&parr[base * 4] = p;
}

// ---------------------------------------------------------------------------
// FUSED layer kernel: per block of 64 nodes, for each type t:
//   (a) each wave aggregates 16 nodes (two interleaved 8-node streams):
//       z_h[d=lane] = sum_e p[e][h] * x[src][d];  v = z/S; split-bf16 -> LDS
//   (b) MFMA K=256 accumulate:  acc += z_t @ B_t   (B staged per 32-k chunk)
// Epilogue: dest[row][col] = gelu((acc + bsum[col]) * 0.25).
// z never touches HBM.  LDS z layout: row lrow (512B), k granule (8 shorts)
// XOR-swizzled by (lrow&31) -> conflict-free b128 reads across 32 rows.
// ---------------------------------------------------------------------------
__global__ __launch_bounds__(256) void k_fused(
    const float* __restrict__ x, const float* __restrict__ parr,
    const int* __restrict__ row_ptr, const int2* __restrict__ sd,
    const ushort_t* __restrict__ Bh, const ushort_t* __restrict__ Bl,
    const float* __restrict__ bias, float* __restrict__ dest)
{
    __shared__ ushort_t zH[64 * 256], zL[64 * 256];   // 32 KB + 32 KB
    __shared__ ushort_t sBh[64 * 32], sBl[64 * 32];   // 4 KB + 4 KB
    const int tid = threadIdx.x;
    const int w = tid >> 6, lane = tid & 63;
    const int l31 = lane & 31, hl = lane >> 5;
    const int rt = w >> 1, ct = w & 1;
    const int rowbase = blockIdx.x * 64;

    floatx16 acc;
    #pragma unroll
    for (int r = 0; r < 16; ++r) acc[r] = 0.f;

    for (int t = 0; t < TT; ++t) {
        // ---- (a) aggregate 16 nodes per wave, two interleaved streams ----
        const int*     srcs = (const int*)(sd + (size_t)t * EPN);
        const floatx4* pt   = (const floatx4*)parr + (size_t)t * EPN;
        const int* rp = row_ptr + t * (NN + 1);
        #pragma unroll 1
        for (int i = 0; i < 8; ++i) {
            int lrA = (w << 4) + i, lrB = lrA + 8;
            int nA = rowbase + lrA, nB = rowbase + lrB;
            float a0 = 0.f, a1 = 0.f, a2 = 0.f, a3 = 0.f;
            float SA0 = 0.f, SA1 = 0.f, SA2 = 0.f, SA3 = 0.f;
            float b0 = 0.f, b1 = 0.f, b2 = 0.f, b3 = 0.f;
            float SB0 = 0.f, SB1 = 0.f, SB2 = 0.f, SB3 = 0.f;
            int eA = 0, eA1 = 0, eB = 0, eB1 = 0;
            if (nA < NN) { eA = rp[nA]; eA1 = rp[nA + 1]; }
            if (nB < NN) { eB = rp[nB]; eB1 = rp[nB + 1]; }
            int m = (eA1 - eA < eB1 - eB) ? (eA1 - eA) : (eB1 - eB);
            #pragma unroll 2
            for (int q = 0; q < m; ++q) {
                int sA_ = srcs[2 * (eA + q)];
                int sB_ = srcs[2 * (eB + q)];
                floatx4 pa = pt[eA + q];
                floatx4 pb = pt[eB + q];
                float xa = x[(size_t)sA_ * 64 + lane];
                float xb = x[(size_t)sB_ * 64 + lane];
                SA0 += pa.x; SA1 += pa.y; SA2 += pa.z; SA3 += pa.w;
                SB0 += pb.x; SB1 += pb.y; SB2 += pb.z; SB3 += pb.w;
                a0 = fmaf(pa.x, xa, a0); a1 = fmaf(pa.y, xa, a1);
                a2 = fmaf(pa.z, xa, a2); a3 = fmaf(pa.w, xa, a3);
                b0 = fmaf(pb.x, xb, b0); b1 = fmaf(pb.y, xb, b1);
                b2 = fmaf(pb.z, xb, b2); b3 = fmaf(pb.w, xb, b3);
            }
            eA += m; eB += m;
            for (; eA < eA1; ++eA) {
                int s = srcs[2 * eA]; floatx4 p = pt[eA];
                float xv = x[(size_t)s * 64 + lane];
                SA0 += p.x; SA1 += p.y; SA2 += p.z; SA3 += p.w;
                a0 = fmaf(p.x, xv, a0); a1 = fmaf(p.y, xv, a1);
                a2 = fmaf(p.z, xv, a2); a3 = fmaf(p.w, xv, a3);
            }
            for (; eB < eB1; ++eB) {
                int s = srcs[2 * eB]; floatx4 p = pt[eB];
                float xv = x[(size_t)s * 64 + lane];
                SB0 += p.x; SB1 += p.y; SB2 += p.z; SB3 += p.w;
                b0 = fmaf(p.x, xv, b0); b1 = fmaf(p.y, xv, b1);
                b2 = fmaf(p.z, xv, b2); b3 = fmaf(p.w, xv, b3);
            }
            // convert + write LDS (k = d*4+h; lane d writes 4 shorts = 8B/plane)
            int gsw = ((lane >> 1) ^ (lrA & 31)) << 3;
            int go = lrA * 256 + gsw + ((lane & 1) << 2);
            {
                float v0 = (nA < NN) ? a0 / SA0 : 0.f;
                float v1 = (nA < NN) ? a1 / SA1 : 0.f;
                float v2 = (nA < NN) ? a2 / SA2 : 0.f;
                float v3 = (nA < NN) ? a3 / SA3 : 0.f;
                unsigned h0 = f2bf(v0), h1 = f2bf(v1), h2 = f2bf(v2), h3 = f2bf(v3);
                *(uint2*)&zH[go] = make_uint2(h0 | (h1 << 16), h2 | (h3 << 16));
                unsigned l0 = f2bf(v0 - bf2f((ushort_t)h0));
                unsigned l1 = f2bf(v1 - bf2f((ushort_t)h1));
                unsigned l2 = f2bf(v2 - bf2f((ushort_t)h2));
                unsigned l3 = f2bf(v3 - bf2f((ushort_t)h3));
                *(uint2*)&zL[go] = make_uint2(l0 | (l1 << 16), l2 | (l3 << 16));
            }
            int gswB = ((lane >> 1) ^ (lrB & 31)) << 3;
            int goB = lrB * 256 + gswB + ((lane & 1) << 2);
            {
                float v0 = (nB < NN) ? b0 / SB0 : 0.f;
                float v1 = (nB < NN) ? b1 / SB1 : 0.f;
                float v2 = (nB < NN) ? b2 / SB2 : 0.f;
                float v3 = (nB < NN) ? b3 / SB3 : 0.f;
                unsigned h0 = f2bf(v0), h1 = f2bf(v1), h2 = f2bf(v2), h3 = f2bf(v3);
                *(uint2*)&zH[goB] = make_uint2(h0 | (h1 << 16), h2 | (h3 << 16));
                unsigned l0 = f2bf(v0 - bf2f((ushort_t)h0));
                unsigned l1 = f2bf(v1 - bf2f((ushort_t)h1));
                unsigned l2 = f2bf(v2 - bf2f((ushort_t)h2));
                unsigned l3 = f2bf(v3 - bf2f((ushort_t)h3));
                *(uint2*)&zL[goB] = make_uint2(l0 | (l1 << 16), l2 | (l3 << 16));
            }
        }
        __syncthreads();
        // ---- (b) GEMM: acc += z_t @ B_t, K=256 in 8 chunks of 32 ----
        const int am = (rt << 5) + l31;
        const int brow = (ct << 5) + l31;
        const int sgb = (l31 ^ (l31 >> 2)) & 3;
        for (int kc = 0; kc < 8; ++kc) {
            {   // stage B chunk: rows = output cols (64), 32 k
                int r = tid >> 2, cg = tid & 3;
                int sg = (r ^ (r >> 2)) & 3;
                size_t gb = (size_t)r * 1024 + t * 256 + kc * 32 + ((cg ^ sg) << 3);
                gl_lds16(Bh + gb, &sBh[r * 32 + cg * 8]);
                gl_lds16(Bl + gb, &sBl[r * 32 + cg * 8]);
            }
            __syncthreads();
            #pragma unroll
            for (int s = 0; s < 2; ++s) {
                int gg = kc * 4 + (s << 1) + hl;
                int ao = am * 256 + ((gg ^ (am & 31)) << 3);
                bf16x8 ah = *(const bf16x8*)&zH[ao];
                bf16x8 al = *(const bf16x8*)&zL[ao];
                int kb = (((s << 1) | hl) ^ sgb) << 3;
                bf16x8 bh = *(const bf16x8*)&sBh[brow * 32 + kb];
                bf16x8 bl = *(const bf16x8*)&sBl[brow * 32 + kb];
                acc = __builtin_amdgcn_mfma_f32_32x32x16_bf16(ah, bh, acc, 0, 0, 0);
                acc = __builtin_amdgcn_mfma_f32_32x32x16_bf16(al, bh, acc, 0, 0, 0);
                acc = __builtin_amdgcn_mfma_f32_32x32x16_bf16(ah, bl, acc, 0, 0, 0);
            }
            __syncthreads();
        }
    }
    // ---- epilogue: mean over types + bias + gelu ----
    int col = (ct << 5) + l31;
    float bv = bias[col];
    #pragma unroll
    for (int r = 0; r < 16; ++r) {
        int row = rowbase + (rt << 5) + (r & 3) + ((r >> 2) << 3) + (hl << 2);
        if (row < NN)
            dest[(size_t)row * 64 + col] = gelu_exact((acc[r] + bv) * 0.25f);
    }
}

// ---------------------------------------------------------------------------
extern "C" void kernel_launch(void* const* d_in, const int* in_sizes, int n_in,
                              void* d_out, int out_size, void* d_ws, size_t ws_size,
                              hipStream_t stream) {
    const float* fm    = (const float*)d_in[0];
    const float* emb   = (const float*)d_in[1];
    const float* lin_w = (const float*)d_in[2];
    const float* lin_b = (const float*)d_in[3];
    const float* ln_g  = (const float*)d_in[4];
    const float* ln_b  = (const float*)d_in[5];
    const float* Wsrc  = (const float*)d_in[6];
    const float* Wdst  = (const float*)d_in[7];
    const float* asrc  = (const float*)d_in[8];
    const float* adst  = (const float*)d_in[9];
    const float* cbias = (const float*)d_in[10];
    const int*   ei    = (const int*)d_in[11];
    float* out = (float*)d_out;
    (void)in_sizes; (void)n_in; (void)out_size; (void)ws_size;

    char* w = (char*)d_ws;
    size_t off = 0;
    auto alloc = [&](size_t bytes) -> void* {
        void* p = w + off;
        off += (bytes + 255) & ~(size_t)255;
        return p;
    };
    ushort_t* wcTh = (ushort_t*)alloc((size_t)LL * 64 * 64 * 2);
    ushort_t* wcTl = (ushort_t*)alloc((size_t)LL * 64 * 64 * 2);
    ushort_t* lwTh = (ushort_t*)alloc((size_t)64 * 256 * 2);
    ushort_t* lwTl = (ushort_t*)alloc((size_t)64 * 256 * 2);
    ushort_t* bpTh = (ushort_t*)alloc((size_t)LL * 64 * 1024 * 2);
    ushort_t* bpTl = (ushort_t*)alloc((size_t)LL * 64 * 1024 * 2);
    float* bsum    = (float*)alloc((size_t)LL * 64 * 4);
    int*   row_ptr = (int*)  alloc((size_t)TT * (NN + 1) * 4);
    int*   cursor  = (int*)  alloc((size_t)TT * NN * 4);
    int2*  sdarr   = (int2*) alloc((size_t)TT * EPN * 8);
    float* parr    = (float*)alloc((size_t)TT * EPN * 4 * 4);
    int*   csum    = (int*)  alloc((size_t)TT * NCH * 4);
    int*   cbase   = (int*)  alloc((size_t)TT * NCH * 4);
    float* x       = (float*)alloc(N64 * 4);
    float* xnew    = (float*)alloc(N64 * 4);
    float* s_all   = (float*)alloc(N64 * 4);
    float* ybuf    = (float*)alloc(N64 * 4);

    hipMemsetAsync(cursor, 0, (size_t)TT * NN * 4, stream);
    k_prep<<<512, 256, 0, stream>>>(Wsrc, Wdst, asrc, adst, cbias, lin_w,
                                    wcTh, wcTl, lwTh, lwTl, bpTh, bpTl, bsum);
    k_hist<<<(TT * EE + 255) / 256, 256, 0, stream>>>(ei, cursor);
    k_scan1<<<TT * NCH, 256, 0, stream>>>(cursor, csum);
    k_scan2<<<1, 64, 0, stream>>>(csum, cbase, row_ptr);
    k_scan3<<<TT * NCH, 256, 0, stream>>>(cursor, cbase, row_ptr);
    k_scatter<<<(TT * EPN + 255) / 256, 256, 0, stream>>>(ei, cursor, sdarr);

    const int GB = (NN + 127) / 128;   // 782 blocks (128 rows each)
    // feature transform: GEMM K=256 (fp32 A, split fused into staging)
    k_gemm_f32a<<<GB, 256, 0, stream>>>(fm, lwTh, lwTl, 256, 256, NN, ybuf);
    k_feat_post<<<NN / 4, 256, 0, stream>>>(ybuf, lin_b, ln_g, ln_b, emb, x);

    const dim3 gp((EPN + 255) / 256, TT);
    const int FB = (NN + 63) / 64;     // 1563 fused blocks
    for (int l = 0; l < LL; ++l) {
        const float* xin = (l == 0) ? x : xnew;
        float* dest = (l == 0) ? xnew : out;
        // collapsed attention-logit projection: s_all = xin @ wcoll_l  [N,64]
        k_gemm_f32a<<<GB, 256, 0, stream>>>(xin, wcTh + l * 4096, wcTl + l * 4096,
                                            64, 64, NN, s_all);
        // edge-parallel p = exp(leaky(logit)) for all 4 types of this layer
        k_edgep<<<gp, 256, 0, stream>>>(s_all, sdarr, parr);
        // fused: aggregate z into LDS + project + bias + gelu -> dest
        k_fused<<<FB, 256, 0, stream>>>(xin, parr, row_ptr, sdarr,
                                        bpTh + (size_t)l * 65536,
                                        bpTl + (size_t)l * 65536,
                                        bsum + l * 64, dest);
    }
}

// Round 7
// 1018.965 us; speedup vs baseline: 1.2296x; 1.2020x over previous
//
#include <hip/hip_runtime.h>
#include <hip/hip_bf16.h>
#include <cstdint>

#define NN   100000
#define TT   4
#define EE   250000
#define LL   2
#define NCH  49            // ceil(NN/2048)
#define N64  ((size_t)NN * 64)

typedef unsigned short ushort_t;
typedef __attribute__((ext_vector_type(8))) short bf16x8;
typedef __attribute__((ext_vector_type(16))) float floatx16;
typedef __attribute__((ext_vector_type(4))) float floatx4;

static __device__ __forceinline__ float gelu_exact(float v) {
    return 0.5f * v * (1.0f + erff(v * 0.7071067811865476f));
}
static __device__ __forceinline__ float wave_sum64(float v) {
    #pragma unroll
    for (int m = 32; m; m >>= 1) v += __shfl_xor(v, m, 64);
    return v;
}
// fp32 -> bf16 round-to-nearest-even (finite inputs only)
static __device__ __forceinline__ ushort_t f2bf(float f) {
    unsigned u = __float_as_uint(f);
    u += 0x7FFFu + ((u >> 16) & 1u);
    return (ushort_t)(u >> 16);
}
static __device__ __forceinline__ float bf2f(ushort_t h) {
    return __uint_as_float((unsigned)h << 16);
}
// async global->LDS 16B (per-lane global addr; LDS dest = wave base + lane*16)
static __device__ __forceinline__ void gl_lds16(const ushort_t* g, ushort_t* l) {
    __builtin_amdgcn_global_load_lds(
        (const __attribute__((address_space(1))) void*)g,
        (__attribute__((address_space(3))) void*)l, 16, 0, 0);
}

// ---------------------------------------------------------------------------
// Prep: GEMM B-operands as TRANSPOSED split-bf16 planes [n][k]:
//  wcollT[l][col][d]  (K=64)   col = t*8+side*4+h, from W·a dot products
//  linwT[c][k]        (K=256)  from lin_w[k][c]
//  bprojT[l][c][kidx] (K=1024) kidx = t*256+h*64+d, val 0.25*W_src[l,t,d,h*64+c]
//  bsum[l][c] = sum_t conv_bias
// ---------------------------------------------------------------------------
__global__ __launch_bounds__(256) void k_prep(
    const float* __restrict__ Wsrc, const float* __restrict__ Wdst,
    const float* __restrict__ asrc, const float* __restrict__ adst,
    const float* __restrict__ cb, const float* __restrict__ lin_w,
    ushort_t* __restrict__ wcTh, ushort_t* __restrict__ wcTl,
    ushort_t* __restrict__ lwTh, ushort_t* __restrict__ lwTl,
    ushort_t* __restrict__ bpTh, ushort_t* __restrict__ bpTl,
    float* __restrict__ bsum)
{
    int id = blockIdx.x * 256 + threadIdx.x;   // grid = 131072 exactly
    {   // bprojT: id = ((((l*4+t)*4+h)*64 + c)*64 + d)
        int d = id & 63;
        int c = (id >> 6) & 63;
        int h = (id >> 12) & 3;
        int t = (id >> 14) & 3;
        int l = (id >> 16) & 1;
        float v = 0.25f * Wsrc[(((l * 4 + t) * 64 + d) * 256) + h * 64 + c];
        int dst = (l * 64 + c) * 1024 + (t * 256 + h * 64 + d);
        ushort_t hh = f2bf(v);
        bpTh[dst] = hh;
        bpTl[dst] = f2bf(v - bf2f(hh));
    }
    if (id < LL * 64 * 64) {   // wcollT
        int d   = id & 63;
        int col = (id >> 6) & 63;
        int l   = (id >> 12) & 1;
        int t = col >> 3, side = (col >> 2) & 1, h = col & 3;
        const float* W = side ? Wdst : Wsrc;
        const float* a = side ? adst : asrc;
        int wb = ((l * 4 + t) * 64 + d) * 256 + h * 64;
        int ab = ((l * 4 + t) * 4 + h) * 64;
        float s = 0.f;
        #pragma unroll 8
        for (int c2 = 0; c2 < 64; ++c2) s = fmaf(W[wb + c2], a[ab + c2], s);
        int dst = (l * 64 + col) * 64 + d;
        ushort_t hh = f2bf(s);
        wcTh[dst] = hh;
        wcTl[dst] = f2bf(s - bf2f(hh));
    }
    if (id < 64 * 256) {       // linwT: c = id>>8, k = id&255
        int k = id & 255, c = id >> 8;
        float v = lin_w[k * 64 + c];
        ushort_t hh = f2bf(v);
        lwTh[c * 256 + k] = hh;
        lwTl[c * 256 + k] = f2bf(v - bf2f(hh));
    }
    if (id < LL * 64) {        // bias_sum
        int l = id >> 6, c = id & 63;
        float s = 0.f;
        for (int t = 0; t < TT; ++t) s += cb[(l * 4 + t) * 64 + c];
        bsum[id] = s;
    }
}

// ---------------------------------------------------------------------------
// CSR build over REAL edges only (self-loops handled inline in k_edge2).
// ---------------------------------------------------------------------------
__global__ void k_hist(const int* __restrict__ ei, int* __restrict__ cursor) {
    int id = blockIdx.x * 256 + threadIdx.x;
    if (id >= TT * EE) return;
    int t = id / EE, e = id - t * EE;
    int d = ei[(t * 2 + 1) * EE + e];
    atomicAdd(&cursor[t * NN + d], 1);
}

__global__ __launch_bounds__(256) void k_scan1(const int* __restrict__ deg,
                                               int* __restrict__ csum) {
    int b = blockIdx.x, t = b / NCH, cc = b - t * NCH;
    int tid = threadIdx.x;
    int base = cc * 2048 + tid * 8;
    int s = 0;
    #pragma unroll
    for (int i = 0; i < 8; ++i) {
        int idx = base + i;
        if (idx < NN) s += deg[t * NN + idx];       // real edges only
    }
    #pragma unroll
    for (int m = 32; m; m >>= 1) s += __shfl_xor(s, m, 64);
    __shared__ int ws4[4];
    int lane = tid & 63, wid = tid >> 6;
    if (lane == 0) ws4[wid] = s;
    __syncthreads();
    if (tid == 0) csum[b] = ws4[0] + ws4[1] + ws4[2] + ws4[3];
}

__global__ void k_scan2(const int* __restrict__ csum, int* __restrict__ cbase,
                        int* __restrict__ row_ptr) {
    int t = threadIdx.x;
    if (t >= TT) return;
    int base = 0;
    for (int c = 0; c < NCH; ++c) {
        cbase[t * NCH + c] = base;
        base += csum[t * NCH + c];
    }
    row_ptr[t * (NN + 1) + NN] = base;   // = EE
}

__global__ __launch_bounds__(256) void k_scan3(int* __restrict__ cursor,
                                               const int* __restrict__ cbase,
                                               int* __restrict__ row_ptr) {
    int b = blockIdx.x, t = b / NCH, cc = b - t * NCH;
    int tid = threadIdx.x, lane = tid & 63, wid = tid >> 6;
    int base = cc * 2048 + tid * 8;
    int vals[8], ts = 0;
    #pragma unroll
    for (int i = 0; i < 8; ++i) {
        int idx = base + i;
        int v = (idx < NN) ? cursor[t * NN + idx] : 0;   // no self slot
        vals[i] = v; ts += v;
    }
    int v = ts;
    #pragma unroll
    for (int off = 1; off < 64; off <<= 1) {
        int u = __shfl_up(v, off, 64);
        if (lane >= off) v += u;
    }
    __shared__ int wt[4];
    if (lane == 63) wt[wid] = v;
    __syncthreads();
    int wbase = 0;
    for (int w = 0; w < wid; ++w) wbase += wt[w];
    int run = cbase[t * NCH + cc] + wbase + (v - ts);
    #pragma unroll
    for (int i = 0; i < 8; ++i) {
        int idx = base + i;
        if (idx < NN) {
            row_ptr[t * (NN + 1) + idx] = run;
            cursor[t * NN + idx] = run;     // becomes scatter write-head
        }
        run += vals[i];
    }
}

__global__ void k_scatter(const int* __restrict__ ei, int* __restrict__ cursor,
                          int2* __restrict__ sd) {
    int id = blockIdx.x * 256 + threadIdx.x;
    if (id >= TT * EE) return;
    int t = id / EE, r = id - t * EE;
    int s = ei[t * 2 * EE + r];
    int d = ei[(t * 2 + 1) * EE + r];
    int pos = atomicAdd(&cursor[t * NN + d], 1);
    sd[(size_t)t * EE + pos] = make_int2(s, d);
}

// ---------------------------------------------------------------------------
// Split-bf16 MFMA GEMM, fp32 A (feature transform + s_all projection).
// C[N,64] = A[N,K] @ B[K,64]; A split into hi/lo during LDS staging.
// LDS: linear 64B rows, XOR chunk-swizzle applied on the source side.
// Fragment layouts (verified m74/m101/m120-lineage):
//   A[m][k]: m=lane&31, k=(lane>>5)*8+j    B[k][n]: n=lane&31, same k
//   C/D: col=lane&31 (+32*ct), row=(reg&3)+8*(reg>>2)+4*(lane>>5)
// ---------------------------------------------------------------------------
__global__ __launch_bounds__(256, 4) void k_gemm_f32a(
    const float* __restrict__ Af,
    const ushort_t* __restrict__ Bhi, const ushort_t* __restrict__ Blo,
    int K, int ldb, int nrows, float* __restrict__ Cout)
{
    constexpr int KC = 32;
    __shared__ ushort_t sAh[128 * 32], sAl[128 * 32];
    __shared__ ushort_t sBh[64 * 32],  sBl[64 * 32];
    const int tid = threadIdx.x;
    const int w = tid >> 6, ln = tid & 63;
    const int l31 = ln & 31, hl = ln >> 5;
    const int rowbase = blockIdx.x * 128;

    floatx16 accv[2];
    #pragma unroll
    for (int ct = 0; ct < 2; ++ct)
        #pragma unroll
        for (int r = 0; r < 16; ++r) accv[ct][r] = 0.f;

    for (int kc = 0; kc < K; kc += KC) {
        __syncthreads();
        // stage A: 128 rows x 32 k (4 chunks of 8), fp32 -> split-bf16
        #pragma unroll
        for (int i = 0; i < 2; ++i) {
            int f = tid + i * 256;           // 0..511
            int r = f >> 2, cg = f & 3;
            int row = rowbase + r;
            int sg = (r ^ (r >> 2)) & 3;
            int sw = r * 32 + ((cg ^ sg) << 3);
            if (row < nrows) {
                size_t ga = (size_t)row * K + kc + cg * 8;
                floatx4 v0 = *(const floatx4*)(Af + ga);
                floatx4 v1 = *(const floatx4*)(Af + ga + 4);
                float vf[8] = {v0.x, v0.y, v0.z, v0.w, v1.x, v1.y, v1.z, v1.w};
                unsigned hu[8], lu[8];
                #pragma unroll
                for (int q = 0; q < 8; ++q) {
                    ushort_t hh = f2bf(vf[q]);
                    hu[q] = hh;
                    lu[q] = f2bf(vf[q] - bf2f(hh));
                }
                uint4 H = make_uint4(hu[0] | (hu[1] << 16), hu[2] | (hu[3] << 16),
                                     hu[4] | (hu[5] << 16), hu[6] | (hu[7] << 16));
                uint4 L = make_uint4(lu[0] | (lu[1] << 16), lu[2] | (lu[3] << 16),
                                     lu[4] | (lu[5] << 16), lu[6] | (lu[7] << 16));
                *(uint4*)&sAh[sw] = H;
                *(uint4*)&sAl[sw] = L;
            } else {
                *(uint4*)&sAh[sw] = make_uint4(0, 0, 0, 0);
                *(uint4*)&sAl[sw] = make_uint4(0, 0, 0, 0);
            }
        }
        // stage B: 64 n-rows x 32 k, both planes, direct-to-LDS
        {
            int r = tid >> 2, cg = tid & 3;
            int sg = (r ^ (r >> 2)) & 3;
            int so = r * 32 + (cg << 3);
            size_t gb = (size_t)r * ldb + kc + ((cg ^ sg) << 3);
            gl_lds16(Bhi + gb, &sBh[so]);
            gl_lds16(Blo + gb, &sBl[so]);
        }
        __syncthreads();
        const int arow = (w << 5) + l31;
        const int sga = (arow ^ (arow >> 2)) & 3;
        const int sgb = (l31 ^ (l31 >> 2)) & 3;
        #pragma unroll
        for (int s = 0; s < 2; ++s) {
            const int c0 = (s << 1) | hl;
            const int ka = (c0 ^ sga) << 3;
            const int kb = (c0 ^ sgb) << 3;
            bf16x8 ah  = *(const bf16x8*)&sAh[arow * 32 + ka];
            bf16x8 al  = *(const bf16x8*)&sAl[arow * 32 + ka];
            bf16x8 bh0 = *(const bf16x8*)&sBh[l31 * 32 + kb];
            bf16x8 bl0 = *(const bf16x8*)&sBl[l31 * 32 + kb];
            bf16x8 bh1 = *(const bf16x8*)&sBh[(32 + l31) * 32 + kb];
            bf16x8 bl1 = *(const bf16x8*)&sBl[(32 + l31) * 32 + kb];
            accv[0] = __builtin_amdgcn_mfma_f32_32x32x16_bf16(ah, bh0, accv[0], 0, 0, 0);
            accv[1] = __builtin_amdgcn_mfma_f32_32x32x16_bf16(ah, bh1, accv[1], 0, 0, 0);
            accv[0] = __builtin_amdgcn_mfma_f32_32x32x16_bf16(al, bh0, accv[0], 0, 0, 0);
            accv[1] = __builtin_amdgcn_mfma_f32_32x32x16_bf16(al, bh1, accv[1], 0, 0, 0);
            accv[0] = __builtin_amdgcn_mfma_f32_32x32x16_bf16(ah, bl0, accv[0], 0, 0, 0);
            accv[1] = __builtin_amdgcn_mfma_f32_32x32x16_bf16(ah, bl1, accv[1], 0, 0, 0);
        }
    }
    #pragma unroll
    for (int ct = 0; ct < 2; ++ct) {
        int col = (ct << 5) + l31;
        #pragma unroll
        for (int r = 0; r < 16; ++r) {
            int row = rowbase + (w << 5) + (r & 3) + ((r >> 2) << 3) + (hl << 2);
            if (row < nrows) Cout[(size_t)row * 64 + col] = accv[ct][r];
        }
    }
}

// ---------------------------------------------------------------------------
// 64-row-tile split-bf16 GEMM for the z projection (memory-BW bound):
// smaller tiles -> 1563 blocks -> ~6 blocks/CU of cross-block overlap across
// the per-kc barrier drains.  Wave layout: rt=w>>1 (row half), ct=w&1 (col
// half); one 32x32 acc per wave (layout verified via k_fused round 6).
// FLAGS bit0: +accbuf; bit1: gelu((v+bias)*0.25)
// ---------------------------------------------------------------------------
template <int FLAGS>
__global__ __launch_bounds__(256, 6) void k_gemm64(
    const ushort_t* __restrict__ Ahi, const ushort_t* __restrict__ Alo,
    const ushort_t* __restrict__ Bhi, const ushort_t* __restrict__ Blo,
    int K, int ldb, int nrows,
    const float* __restrict__ accbuf, const float* __restrict__ bias,
    float* __restrict__ Cout)
{
    constexpr int KC = 32;
    __shared__ ushort_t sAh[64 * 32], sAl[64 * 32];
    __shared__ ushort_t sBh[64 * 32], sBl[64 * 32];
    const int tid = threadIdx.x;
    const int w = tid >> 6, ln = tid & 63;
    const int l31 = ln & 31, hl = ln >> 5;
    const int rt = w >> 1, ct = w & 1;
    const int rowbase = blockIdx.x * 64;

    floatx16 acc;
    #pragma unroll
    for (int r = 0; r < 16; ++r) acc[r] = 0.f;

    for (int kc = 0; kc < K; kc += KC) {
        __syncthreads();
        {   // stage A (64 rows) + B (64 rows), 1 chunk of 8 shorts per thread
            int r = tid >> 2, cg = tid & 3;
            int sg = (r ^ (r >> 2)) & 3;
            int so = r * 32 + (cg << 3);
            int row = rowbase + r;
            if (row < nrows) {
                size_t ga = (size_t)row * K + kc + ((cg ^ sg) << 3);
                gl_lds16(Ahi + ga, &sAh[so]);
                gl_lds16(Alo + ga, &sAl[so]);
            }
            size_t gb = (size_t)r * ldb + kc + ((cg ^ sg) << 3);
            gl_lds16(Bhi + gb, &sBh[so]);
            gl_lds16(Blo + gb, &sBl[so]);
        }
        __syncthreads();
        const int arow = (rt << 5) + l31;
        const int brow = (ct << 5) + l31;
        const int sga = (arow ^ (arow >> 2)) & 3;
        const int sgb = (l31 ^ (l31 >> 2)) & 3;
        #pragma unroll
        for (int s = 0; s < 2; ++s) {
            const int c0 = (s << 1) | hl;
            const int ka = (c0 ^ sga) << 3;
            const int kb = (c0 ^ sgb) << 3;
            bf16x8 ah = *(const bf16x8*)&sAh[arow * 32 + ka];
            bf16x8 al = *(const bf16x8*)&sAl[arow * 32 + ka];
            bf16x8 bh = *(const bf16x8*)&sBh[brow * 32 + kb];
            bf16x8 bl = *(const bf16x8*)&sBl[brow * 32 + kb];
            acc = __builtin_amdgcn_mfma_f32_32x32x16_bf16(ah, bh, acc, 0, 0, 0);
            acc = __builtin_amdgcn_mfma_f32_32x32x16_bf16(al, bh, acc, 0, 0, 0);
            acc = __builtin_amdgcn_mfma_f32_32x32x16_bf16(ah, bl, acc, 0, 0, 0);
        }
    }
    // epilogue (layout verified round 6)
    int col = (ct << 5) + l31;
    float bv = (FLAGS & 2) ? bias[col] : 0.f;
    #pragma unroll
    for (int r = 0; r < 16; ++r) {
        int row = rowbase + (rt << 5) + (r & 3) + ((r >> 2) << 3) + (hl << 2);
        if (row < nrows) {
            size_t idx = (size_t)row * 64 + col;
            float v = acc[r];
            if (FLAGS & 1) v += accbuf[idx];
            if (FLAGS & 2) v = gelu_exact((v + bv) * 0.25f);
            Cout[idx] = v;
        }
    }
}

// ---------------------------------------------------------------------------
// Feature epilogue: x = gelu(LN(y + lin_b)) + l2norm(emb)
// ---------------------------------------------------------------------------
__global__ __launch_bounds__(256) void k_feat_post(
    const float* __restrict__ y, const float* __restrict__ lin_b,
    const float* __restrict__ ln_g, const float* __restrict__ ln_b,
    const float* __restrict__ emb, float* __restrict__ xout)
{
    int n = (blockIdx.x << 2) + (threadIdx.x >> 6);
    int c = threadIdx.x & 63;
    size_t base = (size_t)n * 64 + c;
    float v = y[base] + lin_b[c];
    float mean = wave_sum64(v) * 0.015625f;
    float t = v - mean;
    float var = wave_sum64(t * t) * 0.015625f;
    float vn = t * (1.0f / sqrtf(var + 1e-5f)) * ln_g[c] + ln_b[c];
    float g = gelu_exact(vn);
    float e = emb[base];
    float nrm = sqrtf(wave_sum64(e * e));
    float xv = g + e / fmaxf(nrm, 1e-12f);
    xout[base] = xv;
}

// ---------------------------------------------------------------------------
// Edge-parallel softmax numerator over REAL edges: one lane = one CSR slot.
// p[t][e][h] = exp(leakyrelu(s_all[src][t*8+h] + s_all[dst][t*8+4+h]))
// ---------------------------------------------------------------------------
__global__ __launch_bounds__(256) void k_edgep(
    const float* __restrict__ s_all, const int2* __restrict__ sd,
    float* __restrict__ parr)
{
    int i = blockIdx.x * 256 + threadIdx.x;
    int t = blockIdx.y;
    if (i >= EE) return;
    size_t base = (size_t)t * EE + i;
    int2 e = sd[base];
    const float4 a = *(const float4*)&s_all[(size_t)e.x * 64 + t * 8];
    const float4 b = *(const float4*)&s_all[(size_t)e.y * 64 + t * 8 + 4];
    float l0 = a.x + b.x, l1 = a.y + b.y;
    float l2 = a.z + b.z, l3 = a.w + b.w;
    l0 = l0 > 0.f ? l0 : 0.2f * l0;
    l1 = l1 > 0.f ? l1 : 0.2f * l1;
    l2 = l2 > 0.f ? l2 : 0.2f * l2;
    l3 = l3 > 0.f ? l3 : 0.2f * l3;
    float4 p = make_float4(__expf(l0), __expf(l1), __expf(l2), __expf(l3));
    *(float4*)&parr[base * 4] = p;
}

// ---------------------------------------------------------------------------
// Edge aggregation for a TYPE PAIR (t0, t0+1) -> split-bf16 z planes [N][512].
// One wave per dst node; the two types run as interleaved independent streams.
// Self-loop handled inline: p_self from s_all[n] (broadcast), x[n] coalesced.
// z[n][tt*256+h*64+d] = (p_self*x[n,d] + sum_e p_e,h*x[src_e,d]) / S[n,h]
// ---------------------------------------------------------------------------
__global__ __launch_bounds__(256) void k_edge2(
    const float* __restrict__ x, const float* __restrict__ s_all,
    const float* __restrict__ parr, const int* __restrict__ row_ptr,
    const int2* __restrict__ sd,
    ushort_t* __restrict__ zh, ushort_t* __restrict__ zl, int t0)
{
    int n = (blockIdx.x << 2) + (threadIdx.x >> 6);   // grid = NN/4 exactly
    int lane = threadIdx.x & 63;
    const int tA = t0, tB = t0 + 1;
    int eA  = row_ptr[tA * (NN + 1) + n];
    int eA1 = row_ptr[tA * (NN + 1) + n + 1];
    int eB  = row_ptr[tB * (NN + 1) + n];
    int eB1 = row_ptr[tB * (NN + 1) + n + 1];
    const int*     sA = (const int*)(sd + (size_t)tA * EE);   // .x at stride 2
    const floatx4* pA = (const floatx4*)parr + (size_t)tA * EE;
    const int*     sB = (const int*)(sd + (size_t)tB * EE);
    const floatx4* pB = (const floatx4*)parr + (size_t)tB * EE;
    // self-loop p for both types (same value in all lanes; broadcast loads)
    float xn = x[(size_t)n * 64 + lane];
    float a0, a1, a2, a3, SA0, SA1, SA2, SA3;
    float b0, b1, b2, b3, SB0, SB1, SB2, SB3;
    {
        const float4 sa = *(const float4*)&s_all[(size_t)n * 64 + tA * 8];
        const float4 sb = *(const float4*)&s_all[(size_t)n * 64 + tA * 8 + 4];
        float l0 = sa.x + sb.x, l1 = sa.y + sb.y;
        float l2 = sa.z + sb.z, l3 = sa.w + sb.w;
        l0 = l0 > 0.f ? l0 : 0.2f * l0;  l1 = l1 > 0.f ? l1 : 0.2f * l1;
        l2 = l2 > 0.f ? l2 : 0.2f * l2;  l3 = l3 > 0.f ? l3 : 0.2f * l3;
        SA0 = __expf(l0); SA1 = __expf(l1); SA2 = __expf(l2); SA3 = __expf(l3);
        a0 = SA0 * xn; a1 = SA1 * xn; a2 = SA2 * xn; a3 = SA3 * xn;
    }
    {
        const float4 sa = *(const float4*)&s_all[(size_t)n * 64 + tB * 8];
        const float4 sb = *(const float4*)&s_all[(size_t)n * 64 + tB * 8 + 4];
        float l0 = sa.x + sb.x, l1 = sa.y + sb.y;
        float l2 = sa.z + sb.z, l3 = sa.w + sb.w;
        l0 = l0 > 0.f ? l0 : 0.2f * l0;  l1 = l1 > 0.f ? l1 : 0.2f * l1;
        l2 = l2 > 0.f ? l2 : 0.2f * l2;  l3 = l3 > 0.f ? l3 : 0.2f * l3;
        SB0 = __expf(l0); SB1 = __expf(l1); SB2 = __expf(l2); SB3 = __expf(l3);
        b0 = SB0 * xn; b1 = SB1 * xn; b2 = SB2 * xn; b3 = SB3 * xn;
    }
    int m = (eA1 - eA < eB1 - eB) ? (eA1 - eA) : (eB1 - eB);
    #pragma unroll 2
    for (int i = 0; i < m; ++i) {
        int sA_ = sA[2 * (eA + i)];                       // wave-uniform
        int sB_ = sB[2 * (eB + i)];
        floatx4 pa = pA[eA + i];                          // wave-uniform 16B
        floatx4 pb = pB[eB + i];
        float xa = x[(size_t)sA_ * 64 + lane];            // coalesced 256B
        float xb = x[(size_t)sB_ * 64 + lane];
        SA0 += pa.x; SA1 += pa.y; SA2 += pa.z; SA3 += pa.w;
        SB0 += pb.x; SB1 += pb.y; SB2 += pb.z; SB3 += pb.w;
        a0 = fmaf(pa.x, xa, a0); a1 = fmaf(pa.y, xa, a1);
        a2 = fmaf(pa.z, xa, a2); a3 = fmaf(pa.w, xa, a3);
        b0 = fmaf(pb.x, xb, b0); b1 = fmaf(pb.y, xb, b1);
        b2 = fmaf(pb.z, xb, b2); b3 = fmaf(pb.w, xb, b3);
    }
    eA += m; eB += m;
    for (; eA < eA1; ++eA) {
        int s = sA[2 * eA]; floatx4 p = pA[eA];
        float xv = x[(size_t)s * 64 + lane];
        SA0 += p.x; SA1 += p.y; SA2 += p.z; SA3 += p.w;
        a0 = fmaf(p.x, xv, a0); a1 = fmaf(p.y, xv, a1);
        a2 = fmaf(p.z, xv, a2); a3 = fmaf(p.w, xv, a3);
    }
    for (; eB < eB1; ++eB) {
        int s = sB[2 * eB]; floatx4 p = pB[eB];
        float xv = x[(size_t)s * 64 + lane];
        SB0 += p.x; SB1 += p.y; SB2 += p.z; SB3 += p.w;
        b0 = fmaf(p.x, xv, b0); b1 = fmaf(p.y, xv, b1);
        b2 = fmaf(p.z, xv, b2); b3 = fmaf(p.w, xv, b3);
    }
    size_t zb = (size_t)n * 512 + lane;
    {
        float v0 = a0 / SA0, v1 = a1 / SA1, v2 = a2 / SA2, v3 = a3 / SA3;
        ushort_t h0 = f2bf(v0), h1 = f2bf(v1), h2 = f2bf(v2), h3 = f2bf(v3);
        zh[zb]       = h0;  zl[zb]       = f2bf(v0 - bf2f(h0));
        zh[zb + 64]  = h1;  zl[zb + 64]  = f2bf(v1 - bf2f(h1));
        zh[zb + 128] = h2;  zl[zb + 128] = f2bf(v2 - bf2f(h2));
        zh[zb + 192] = h3;  zl[zb + 192] = f2bf(v3 - bf2f(h3));
    }
    {
        size_t zc = zb + 256;
        float v0 = b0 / SB0, v1 = b1 / SB1, v2 = b2 / SB2, v3 = b3 / SB3;
        ushort_t h0 = f2bf(v0), h1 = f2bf(v1), h2 = f2bf(v2), h3 = f2bf(v3);
        zh[zc]       = h0;  zl[zc]       = f2bf(v0 - bf2f(h0));
        zh[zc + 64]  = h1;  zl[zc + 64]  = f2bf(v1 - bf2f(h1));
        zh[zc + 128] = h2;  zl[zc + 128] = f2bf(v2 - bf2f(h2));
        zh[zc + 192] = h3;  zl[zc + 192] = f2bf(v3 - bf2f(h3));
    }
}

// ---------------------------------------------------------------------------
extern "C" void kernel_launch(void* const* d_in, const int* in_sizes, int n_in,
                              void* d_out, int out_size, void* d_ws, size_t ws_size,
                              hipStream_t stream) {
    const float* fm    = (const float*)d_in[0];
    const float* emb   = (const float*)d_in[1];
    const float* lin_w = (const float*)d_in[2];
    const float* lin_b = (const float*)d_in[3];
    const float* ln_g  = (const float*)d_in[4];
    const float* ln_b  = (const float*)d_in[5];
    const float* Wsrc  = (const float*)d_in[6];
    const float* Wdst  = (const float*)d_in[7];
    const float* asrc  = (const float*)d_in[8];
    const float* adst  = (const float*)d_in[9];
    const float* cbias = (const float*)d_in[10];
    const int*   ei    = (const int*)d_in[11];
    float* out = (float*)d_out;
    (void)in_sizes; (void)n_in; (void)out_size; (void)ws_size;

    char* w = (char*)d_ws;
    size_t off = 0;
    auto alloc = [&](size_t bytes) -> void* {
        void* p = w + off;
        off += (bytes + 255) & ~(size_t)255;
        return p;
    };
    ushort_t* wcTh = (ushort_t*)alloc((size_t)LL * 64 * 64 * 2);
    ushort_t* wcTl = (ushort_t*)alloc((size_t)LL * 64 * 64 * 2);
    ushort_t* lwTh = (ushort_t*)alloc((size_t)64 * 256 * 2);
    ushort_t* lwTl = (ushort_t*)alloc((size_t)64 * 256 * 2);
    ushort_t* bpTh = (ushort_t*)alloc((size_t)LL * 64 * 1024 * 2);
    ushort_t* bpTl = (ushort_t*)alloc((size_t)LL * 64 * 1024 * 2);
    float* bsum    = (float*)alloc((size_t)LL * 64 * 4);
    int*   row_ptr = (int*)  alloc((size_t)TT * (NN + 1) * 4);
    int*   cursor  = (int*)  alloc((size_t)TT * NN * 4);
    int2*  sdarr   = (int2*) alloc((size_t)TT * EE * 8);
    float* parr    = (float*)alloc((size_t)TT * EE * 4 * 4);
    int*   csum    = (int*)  alloc((size_t)TT * NCH * 4);
    int*   cbase   = (int*)  alloc((size_t)TT * NCH * 4);
    float* x       = (float*)alloc(N64 * 4);
    float* s_all   = (float*)alloc(N64 * 4);
    float* accB    = (float*)alloc(N64 * 4);
    // z split planes for one type pair: [N][512] hi + lo  (204.8 MB)
    size_t planeE = (size_t)NN * 512;
    ushort_t* zh = (ushort_t*)alloc(2 * planeE * 2);
    ushort_t* zl = zh + planeE;

    hipMemsetAsync(cursor, 0, (size_t)TT * NN * 4, stream);
    k_prep<<<512, 256, 0, stream>>>(Wsrc, Wdst, asrc, adst, cbias, lin_w,
                                    wcTh, wcTl, lwTh, lwTl, bpTh, bpTl, bsum);
    k_hist<<<(TT * EE + 255) / 256, 256, 0, stream>>>(ei, cursor);
    k_scan1<<<TT * NCH, 256, 0, stream>>>(cursor, csum);
    k_scan2<<<1, 64, 0, stream>>>(csum, cbase, row_ptr);
    k_scan3<<<TT * NCH, 256, 0, stream>>>(cursor, cbase, row_ptr);
    k_scatter<<<(TT * EE + 255) / 256, 256, 0, stream>>>(ei, cursor, sdarr);

    const int GB  = (NN + 127) / 128;  // 782 blocks (128 rows each)
    const int GB2 = (NN + 63) / 64;    // 1563 blocks (64 rows each)
    // feature transform: GEMM K=256 (fp32 A, split fused into staging)
    k_gemm_f32a<<<GB, 256, 0, stream>>>(fm, lwTh, lwTl, 256, 256, NN, accB);
    k_feat_post<<<NN / 4, 256, 0, stream>>>(accB, lin_b, ln_g, ln_b, emb, x);

    const dim3 gp((EE + 255) / 256, TT);
    for (int l = 0; l < LL; ++l) {
        float* dest = (l == 0) ? x : out;
        // collapsed attention-logit projection: s_all = x @ wcoll_l  [N,64]
        k_gemm_f32a<<<GB, 256, 0, stream>>>(x, wcTh + l * 4096, wcTl + l * 4096,
                                            64, 64, NN, s_all);
        // edge-parallel p = exp(leaky(logit)) over real edges, all 4 types
        k_edgep<<<gp, 256, 0, stream>>>(s_all, sdarr, parr);
        const ushort_t* Bh = bpTh + (size_t)l * 65536;
        const ushort_t* Bl = bpTl + (size_t)l * 65536;
        // pair 0 (types 0,1): aggregate + GEMM K=512 -> accB
        k_edge2<<<NN / 4, 256, 0, stream>>>(x, s_all, parr, row_ptr, sdarr,
                                            zh, zl, 0);
        k_gemm64<0><<<GB2, 256, 0, stream>>>(zh, zl, Bh, Bl, 512, 1024, NN,
                                             nullptr, nullptr, accB);
        // pair 1 (types 2,3): aggregate + GEMM K=512 + acc + gelu -> dest
        k_edge2<<<NN / 4, 256, 0, stream>>>(x, s_all, parr, row_ptr, sdarr,
                                            zh, zl, 2);
        k_gemm64<3><<<GB2, 256, 0, stream>>>(zh, zl, Bh + 512, Bl + 512, 512, 1024,
                                             NN, accB, bsum + l * 64, dest);
    }
}